// Round 1
// baseline (745.852 us; speedup 1.0000x reference)
//
#include <hip/hip_runtime.h>

#define BATCH   262144
#define NCODE   1024
#define DIM     64
#define BLOCK   256
#define NBLK    (BATCH / BLOCK)   // 1024 blocks

// ws layout: [0, 8192): double partial[1024]; [8192, 12288): float c2[1024]

// c2[k] = np.sum(cb[k]*cb[k]) with numpy's pairwise order (8 accumulators, n=64)
__global__ void c2_kernel(const float* __restrict__ cb, float* __restrict__ c2) {
    int k = blockIdx.x * blockDim.x + threadIdx.x;
    if (k >= NCODE) return;
    const float* row = cb + (size_t)k * DIM;
    float r[8];
#pragma unroll
    for (int j = 0; j < 8; ++j) r[j] = __fmul_rn(row[j], row[j]);
#pragma unroll
    for (int i = 8; i < DIM; i += 8) {
#pragma unroll
        for (int j = 0; j < 8; ++j) r[j] = __fadd_rn(r[j], __fmul_rn(row[i + j], row[i + j]));
    }
    c2[k] = __fadd_rn(__fadd_rn(__fadd_rn(r[0], r[1]), __fadd_rn(r[2], r[3])),
                      __fadd_rn(__fadd_rn(r[4], r[5]), __fadd_rn(r[6], r[7])));
}

__global__ __launch_bounds__(BLOCK) void vq_kernel(
        const float* __restrict__ z, const float* __restrict__ cb,
        const float* __restrict__ c2, float* __restrict__ out_zq,
        float* __restrict__ out_idx, double* __restrict__ partial) {
    const int b = blockIdx.x * BLOCK + threadIdx.x;

    // load my row of z into registers (16 x float4)
    float zr[DIM];
    const float4* zv = (const float4*)(z + (size_t)b * DIM);
#pragma unroll
    for (int i = 0; i < DIM / 4; ++i) {
        float4 v = zv[i];
        zr[4 * i + 0] = v.x; zr[4 * i + 1] = v.y;
        zr[4 * i + 2] = v.z; zr[4 * i + 3] = v.w;
    }

    // z2 = np.sum(z*z, axis=1) — numpy pairwise, n=64 (order not argmin-critical, but exact is free)
    float r[8];
#pragma unroll
    for (int j = 0; j < 8; ++j) r[j] = __fmul_rn(zr[j], zr[j]);
#pragma unroll
    for (int i = 8; i < DIM; i += 8) {
#pragma unroll
        for (int j = 0; j < 8; ++j) r[j] = __fadd_rn(r[j], __fmul_rn(zr[i + j], zr[i + j]));
    }
    const float z2 = __fadd_rn(__fadd_rn(__fadd_rn(r[0], r[1]), __fadd_rn(r[2], r[3])),
                               __fadd_rn(__fadd_rn(r[4], r[5]), __fadd_rn(r[6], r[7])));

    // argmin_k of rnd(rnd(z2 - 2*dot(z,cb_k)) + c2_k); dot = sequential fp32 FMA (sgemm order)
    float best = __builtin_inff();
    int bestk = 0;
    for (int k = 0; k < NCODE; ++k) {
        const float* ck = cb + (size_t)k * DIM;   // k is wave-uniform -> scalar loads
        float acc = 0.0f;
#pragma unroll
        for (int d = 0; d < DIM; ++d) acc = __fmaf_rn(zr[d], ck[d], acc);
        const float t = __fmaf_rn(-2.0f, acc, z2);        // == rnd(z2 - 2*acc), single rounding
        const float dist = __fadd_rn(t, c2[k]);
        if (dist < best) { best = dist; bestk = k; }      // strict < : first-index tie-break
    }

    // epilogue: z_q gather, straight-through output, loss partial
    const float* cq = cb + (size_t)bestk * DIM;
    double lsum = 0.0;
    float4* ov = (float4*)(out_zq + (size_t)b * DIM);
#pragma unroll
    for (int i = 0; i < DIM / 4; ++i) {
        float q[4], o[4];
#pragma unroll
        for (int j = 0; j < 4; ++j) q[j] = cq[4 * i + j];
#pragma unroll
        for (int j = 0; j < 4; ++j) {
            const float t = __fsub_rn(q[j], zr[4 * i + j]);   // z_q - z (rounded)
            o[j] = __fadd_rn(zr[4 * i + j], t);               // z + (z_q - z)
            lsum += (double)t * (double)t;
        }
        float4 vv; vv.x = o[0]; vv.y = o[1]; vv.z = o[2]; vv.w = o[3];
        ov[i] = vv;
    }
    out_idx[b] = (float)bestk;

    // block-level deterministic loss reduction
    __shared__ double sred[BLOCK];
    sred[threadIdx.x] = lsum;
    __syncthreads();
#pragma unroll
    for (int s = BLOCK / 2; s > 0; s >>= 1) {
        if (threadIdx.x < s) sred[threadIdx.x] += sred[threadIdx.x + s];
        __syncthreads();
    }
    if (threadIdx.x == 0) partial[blockIdx.x] = sred[0];
}

__global__ void loss_kernel(const double* __restrict__ partial, float* __restrict__ out_loss) {
    __shared__ double sred[256];
    double s = 0.0;
    for (int i = threadIdx.x; i < NBLK; i += 256) s += partial[i];
    sred[threadIdx.x] = s;
    __syncthreads();
#pragma unroll
    for (int st = 128; st > 0; st >>= 1) {
        if (threadIdx.x < st) sred[threadIdx.x] += sred[threadIdx.x + st];
        __syncthreads();
    }
    if (threadIdx.x == 0) {
        const double mean = sred[0] / (double)((size_t)BATCH * DIM);
        const float L = (float)mean;                       // codebook_loss == commitment_loss numerically
        out_loss[0] = __fadd_rn(L, __fmul_rn(0.25f, L));   // L + 0.25*L, fp32 rounding like ref
    }
}

extern "C" void kernel_launch(void* const* d_in, const int* in_sizes, int n_in,
                              void* d_out, int out_size, void* d_ws, size_t ws_size,
                              hipStream_t stream) {
    (void)in_sizes; (void)n_in; (void)out_size; (void)ws_size;
    const float* z  = (const float*)d_in[0];
    const float* cb = (const float*)d_in[1];
    float* out      = (float*)d_out;
    float* out_zq   = out;                                  // [BATCH*DIM)
    float* out_loss = out + (size_t)BATCH * DIM;            // [1]
    float* out_idx  = out + (size_t)BATCH * DIM + 1;        // [BATCH]
    double* partial = (double*)d_ws;                        // 1024 doubles
    float* c2       = (float*)((char*)d_ws + NBLK * sizeof(double));

    c2_kernel<<<NCODE / 256, 256, 0, stream>>>(cb, c2);
    vq_kernel<<<NBLK, BLOCK, 0, stream>>>(z, cb, c2, out_zq, out_idx, partial);
    loss_kernel<<<1, 256, 0, stream>>>(partial, out_loss);
}